// Round 4
// baseline (56.951 us; speedup 1.0000x reference)
//
#include <hip/hip_runtime.h>
#include <hip/hip_bf16.h>

// Rotation perturbation = dense tent-weight matmul in the reference; the tent
// max(0, 1-|off|) has support < 2, so the dense [B,N,N] matmul collapses
// exactly to 4-tap bilinear interpolation with zero padding (edge taps keep
// partial, un-normalized weights — matching the dense formula).
//
// Dtypes (established R1-R3): inputs f32, output f32; the test compares in
// bf16 space (absmax 0.00390625 = one bf16 ulp at ~1.0 => exact).
//
// R4: 4 pixels/thread (float4 store), __sincosf fast path, block=64 so the
// 300 single-wave workgroups spread across CUs. Kernel is launch-overhead
// bound; measured dur_us is dominated by the harness's 268 MB ws-poison fill
// (~39.6 us at 85% HBM peak) which we cannot control.
//
// Shapes: theta [B=4], image [C=3, H=80, W=80]. Output [B, C, H, W] = 76800.

#define RP_B 4
#define RP_C 3
#define RP_H 80
#define RP_W 80
#define RP_XV 4                      // pixels per thread along x
#define RP_XQ (RP_W / RP_XV)         // 20 x-quads per row

__global__ __launch_bounds__(64)
void RotationPerturbationLayer_7464653160916_kernel(
    const float* __restrict__ theta,
    const float* __restrict__ image,
    float* __restrict__ out)
{
    const int N = RP_H * RP_W;
    const int totalT = RP_B * RP_C * RP_H * RP_XQ;   // 19200 threads
    int t = blockIdx.x * blockDim.x + threadIdx.x;
    if (t >= totalT) return;

    int xq = t % RP_XQ;
    int y  = (t / RP_XQ) % RP_H;
    int c  = (t / (RP_XQ * RP_H)) % RP_C;
    int b  =  t / (RP_XQ * RP_H * RP_C);
    int xb = xq * RP_XV;

    // theta in degrees -> radians; fast sincos (err ~2^-21, invisible in bf16)
    float th = theta[b] * (3.14159265358979323846f / 180.0f);
    float s, co;
    __sincosf(th, &s, &co);

    const float cx = (RP_W - 1) * 0.5f;
    const float cy = (RP_H - 1) * 0.5f;
    float xr = (float)xb - cx;
    float yr = (float)y - cy;
    // rotation [[cos, sin], [-sin, cos]]; incremental per +1 in x:
    //   sx += cos, sy -= sin
    float sx =  co * xr + s  * yr + cx;
    float sy = -s  * xr + co * yr + cy;

    const float* img = image + c * N;
    float4 res;
    float* resp = &res.x;

    #pragma unroll
    for (int j = 0; j < RP_XV; ++j) {
        float fx0 = floorf(sx);
        float fy0 = floorf(sy);
        int x0 = (int)fx0;
        int y0 = (int)fy0;
        float ax = sx - fx0;
        float ay = sy - fy0;
        float wx0 = 1.0f - ax, wx1 = ax;
        float wy0 = 1.0f - ay, wy1 = ay;

        float acc = 0.0f;
        // Zero-padded 4-tap gather; unsigned compare handles negatives.
        if ((unsigned)y0 < (unsigned)RP_H) {
            const float* row = img + y0 * RP_W;
            if ((unsigned)x0       < (unsigned)RP_W) acc += wy0 * wx0 * row[x0];
            if ((unsigned)(x0 + 1) < (unsigned)RP_W) acc += wy0 * wx1 * row[x0 + 1];
        }
        if ((unsigned)(y0 + 1) < (unsigned)RP_H) {
            const float* row = img + (y0 + 1) * RP_W;
            if ((unsigned)x0       < (unsigned)RP_W) acc += wy1 * wx0 * row[x0];
            if ((unsigned)(x0 + 1) < (unsigned)RP_W) acc += wy1 * wx1 * row[x0 + 1];
        }
        resp[j] = acc;

        sx += co;
        sy -= s;
    }

    // xb % 4 == 0 and W % 4 == 0 -> 16B-aligned coalesced store
    float4* outv = (float4*)(out + ((b * RP_C + c) * RP_H + y) * RP_W + xb);
    *outv = res;
}

extern "C" void kernel_launch(void* const* d_in, const int* in_sizes, int n_in,
                              void* d_out, int out_size, void* d_ws, size_t ws_size,
                              hipStream_t stream) {
    // theta has 4 elements, image 19200 — disambiguate by size for safety.
    const float* theta;
    const float* image;
    if (in_sizes[0] == RP_B) {
        theta = (const float*)d_in[0];
        image = (const float*)d_in[1];
    } else {
        theta = (const float*)d_in[1];
        image = (const float*)d_in[0];
    }
    float* out = (float*)d_out;

    const int totalT = RP_B * RP_C * RP_H * RP_XQ;   // 19200
    dim3 block(64);
    dim3 grid((totalT + 63) / 64);                   // 300 blocks, 1 wave each
    RotationPerturbationLayer_7464653160916_kernel<<<grid, block, 0, stream>>>(theta, image, out);
}